// Round 3
// baseline (1214.361 us; speedup 1.0000x reference)
//
#include <hip/hip_runtime.h>
#include <math.h>

// FrontierLayerVN: gather -> GVPerceptronVN -> GVLinear(scalar out)
// fp32 pipeline: k0 (Wfuse=Ws1@Wg) -> k1 (vh/vnorm/ovec) -> k2 (fused GEMM+gate+VNrelu+out)
// ws layout (floats): vnorm M*64 | ovec M*96 | wfuse 320*32

#define NSV 0.2f
#define NSS 0.01f

// ---------------- K0: Wfuse = Ws1 @ Wg (320x128 @ 128x32) ----------------
__global__ __launch_bounds__(256) void k0_kernel(
    const float* __restrict__ Ws1,   // 320 x 128
    const float* __restrict__ Wg,    // 128 x 32
    float* __restrict__ Wfuse)       // 320 x 32
{
    const int K = blockIdx.x * 8 + (threadIdx.x >> 5);
    const int o = threadIdx.x & 31;
    float s = 0.f;
    for (int j = 0; j < 128; ++j)
        s += Ws1[K*128 + j] * Wg[j*32 + o];
    Wfuse[K*32 + o] = s;
}

// ---------------- K1: vh / vnorm / out_vec ----------------
// 32 rows per block, 256 threads. LDS reads vectorized to b128 (c/h unroll 4).
__global__ __launch_bounds__(256) void k1_kernel(
    const float* __restrict__ hvec,   // N x 64 x 3
    const int*   __restrict__ idx,    // M
    const float* __restrict__ Wv1,    // 64 x 64  [c][h]
    const float* __restrict__ Wv2,    // 64 x 32  [h][o]
    float* __restrict__ vnorm_ws,     // M x 64
    float* __restrict__ ovec_ws,      // M x 96
    int M)
{
    __shared__ __align__(16) float sWv1[64*64];
    __shared__ __align__(16) float sWv2[64*32];
    __shared__ __align__(16) float sv[32*200];   // stride 200: 16B-aligned rows, 2-way alias only
    __shared__ __align__(16) int sidx[32];

    const int tid  = threadIdx.x;
    const int row0 = blockIdx.x * 32;

    #pragma unroll
    for (int p = 0; p < 4; ++p) {
        int lin = p*256 + tid;
        *(float4*)&sWv1[lin*4] = *(const float4*)&Wv1[lin*4];
    }
    #pragma unroll
    for (int p = 0; p < 2; ++p) {
        int lin = p*256 + tid;
        *(float4*)&sWv2[lin*4] = *(const float4*)&Wv2[lin*4];
    }
    if (tid < 32) {
        int m = row0 + tid;
        sidx[tid] = idx[m < M ? m : M-1];
    }
    __syncthreads();

    // gather 32 vec rows (192 floats = 48 float4 each), coalesced float4
    #pragma unroll
    for (int p = 0; p < 6; ++p) {
        int lin = p*256 + tid;           // float4 index, 1536 total
        int r = lin / 48, e4 = lin % 48;
        *(float4*)&sv[r*200 + e4*4] = *(const float4*)&hvec[(size_t)sidx[r]*192 + e4*4];
    }
    __syncthreads();

    // vh GEMM: thread = (ty: 2 rows, tx: 4 h) x 3 comps, c unrolled by 4
    const int tx = tid & 15;
    const int ty = tid >> 4;
    float acc[2][4][3];
    #pragma unroll
    for (int a = 0; a < 2; ++a)
        #pragma unroll
        for (int b = 0; b < 4; ++b)
            #pragma unroll
            for (int c = 0; c < 3; ++c) acc[a][b][c] = 0.f;

    for (int c = 0; c < 64; c += 4) {
        float xa[2][12];
        #pragma unroll
        for (int rr = 0; rr < 2; ++rr) {
            int base = (ty*2 + rr)*200 + c*3;
            *(float4*)&xa[rr][0] = *(const float4*)&sv[base];
            *(float4*)&xa[rr][4] = *(const float4*)&sv[base+4];
            *(float4*)&xa[rr][8] = *(const float4*)&sv[base+8];
        }
        #pragma unroll
        for (int j = 0; j < 4; ++j) {
            float4 w4 = *(const float4*)&sWv1[(c+j)*64 + tx*4];
            float wv[4] = {w4.x, w4.y, w4.z, w4.w};
            #pragma unroll
            for (int rr = 0; rr < 2; ++rr)
                #pragma unroll
                for (int hh = 0; hh < 4; ++hh)
                    #pragma unroll
                    for (int x = 0; x < 3; ++x)
                        acc[rr][hh][x] += xa[rr][j*3 + x] * wv[hh];
        }
    }

    // vnorm = ||vh|| -> ws (float4 per row-chunk)
    #pragma unroll
    for (int rr = 0; rr < 2; ++rr) {
        int m = row0 + ty*2 + rr;
        float4 vn;
        vn.x = sqrtf(acc[rr][0][0]*acc[rr][0][0] + acc[rr][0][1]*acc[rr][0][1] + acc[rr][0][2]*acc[rr][0][2]);
        vn.y = sqrtf(acc[rr][1][0]*acc[rr][1][0] + acc[rr][1][1]*acc[rr][1][1] + acc[rr][1][2]*acc[rr][1][2]);
        vn.z = sqrtf(acc[rr][2][0]*acc[rr][2][0] + acc[rr][2][1]*acc[rr][2][1] + acc[rr][2][2]*acc[rr][2][2]);
        vn.w = sqrtf(acc[rr][3][0]*acc[rr][3][0] + acc[rr][3][1]*acc[rr][3][1] + acc[rr][3][2]*acc[rr][3][2]);
        if (m < M) *(float4*)&vnorm_ws[(size_t)m*64 + tx*4] = vn;
    }

    __syncthreads();   // all reads of sv (vec) done
    // write vh into sv: layout [r][h*3+x]
    #pragma unroll
    for (int rr = 0; rr < 2; ++rr)
        #pragma unroll
        for (int hh = 0; hh < 4; ++hh)
            #pragma unroll
            for (int x = 0; x < 3; ++x)
                sv[(ty*2 + rr)*200 + (tx*4 + hh)*3 + x] = acc[rr][hh][x];
    __syncthreads();

    // out_vec GEMM: thread = (r2: 1 row, to: 4 o) x 3 comps, h unrolled by 4
    const int to = tid & 7;
    const int r2 = tid >> 3;
    float oa[4][3];
    #pragma unroll
    for (int a = 0; a < 4; ++a)
        #pragma unroll
        for (int c = 0; c < 3; ++c) oa[a][c] = 0.f;

    for (int h = 0; h < 64; h += 4) {
        float xa[12];
        int base = r2*200 + h*3;
        *(float4*)&xa[0] = *(const float4*)&sv[base];
        *(float4*)&xa[4] = *(const float4*)&sv[base+4];
        *(float4*)&xa[8] = *(const float4*)&sv[base+8];
        #pragma unroll
        for (int j = 0; j < 4; ++j) {
            float4 w4 = *(const float4*)&sWv2[(h+j)*32 + to*4];
            float wv[4] = {w4.x, w4.y, w4.z, w4.w};
            #pragma unroll
            for (int oo = 0; oo < 4; ++oo) {
                oa[oo][0] += xa[j*3+0]*wv[oo];
                oa[oo][1] += xa[j*3+1]*wv[oo];
                oa[oo][2] += xa[j*3+2]*wv[oo];
            }
        }
    }
    int m2 = row0 + r2;
    if (m2 < M) {
        float t[12];
        #pragma unroll
        for (int oo = 0; oo < 4; ++oo)
            #pragma unroll
            for (int x = 0; x < 3; ++x) t[oo*3+x] = oa[oo][x];
        float4* dst = (float4*)&ovec_ws[(size_t)m2*96 + to*12];
        dst[0] = make_float4(t[0], t[1], t[2],  t[3]);
        dst[1] = make_float4(t[4], t[5], t[6],  t[7]);
        dst[2] = make_float4(t[8], t[9], t[10], t[11]);
    }
}

// ---------------- K2 (fused): osca GEMM + gate + VNLeakyReLU + layer2 scalar ----------------
// 128 rows x 128 cols per block, 256 threads, KT=32, 8x8 acc + 8x2 gate acc.
// X tile stored TRANSPOSED in LDS (b128 a-reads). Gate folded via Wfuse = Ws1@Wg.
// Epilogue: per-thread sca leaky-dot (shuffle-reduced), then per-o phases on 64-row chunks.
__global__ __launch_bounds__(256) void k2_kernel(
    const float* __restrict__ hsca,     // N x 256
    const int*   __restrict__ idx,
    const float* __restrict__ Ws1,      // 320 x 128
    const float* __restrict__ vnorm_ws, // M x 64
    const float* __restrict__ ovec_ws,  // M x 96
    const float* __restrict__ Wfuse,    // 320 x 32
    const float* __restrict__ bg,       // 32
    const float* __restrict__ Wd,       // 32 x 32 [c][o]
    const float* __restrict__ Wv12,     // 32 x 32 [c][h]
    const float* __restrict__ Ws2,      // 160
    float* __restrict__ out,            // M
    int M)
{
    __shared__ __align__(16) float sXT[32*132];   // transposed X tile: [k][row]
    __shared__ __align__(16) float sW[32*128];    // Ws1 tile [k][col]
    __shared__ __align__(16) float sG[32*32];     // Wfuse tile [k][o]
    __shared__ __align__(16) float sV[64*101];    // epilogue v1/v2 chunk (64 rows)
    __shared__ __align__(16) float sWd[32*32];
    __shared__ __align__(16) float sW12[32*32];
    __shared__ __align__(16) float sWs2[160];
    __shared__ __align__(16) float sSca[128];
    __shared__ __align__(16) int   sidx[128];

    const int tid  = threadIdx.x;
    const int row0 = blockIdx.x * 128;
    const int tx = tid & 15;
    const int ty = tid >> 4;

    if (tid < 128) {
        int m = row0 + tid;
        sidx[tid] = idx[m < M ? m : M-1];
    }
    // small weights staged once (read-only throughout)
    {
        int lin = tid;
        *(float4*)&sWd[lin*4]  = *(const float4*)&Wd[lin*4];      // 1024 floats
        *(float4*)&sW12[lin*4] = *(const float4*)&Wv12[lin*4];    // 1024 floats
        if (tid < 160) sWs2[tid] = Ws2[tid];
    }
    __syncthreads();   // sidx readable

    // per-thread staging descriptors (4 float4 of X, 4 float4 of W, 1 float4 of G per tile)
    const float* xptr[4];   // hsca gather base (kt >= 2)
    const float* vptr[4];   // vnorm base (kt < 2)
    #pragma unroll
    for (int p = 0; p < 4; ++p) {
        int lin = p*256 + tid;       // float4 index into 128x32 tile
        int r = lin >> 3, c4 = lin & 7;
        int m = row0 + r; if (m >= M) m = M - 1;
        xptr[p] = hsca + (size_t)sidx[r]*256 + c4*4;
        vptr[p] = vnorm_ws + (size_t)m*64 + c4*4;
    }
    const float* wsrc = Ws1 + (size_t)tid*4;
    const float* gsrc = Wfuse + (size_t)tid*4;

    float4 xr[4], wr[4], gr;

    auto load_tile = [&](int kt) {
        if (kt < 2) {
            #pragma unroll
            for (int p = 0; p < 4; ++p) xr[p] = *(const float4*)(vptr[p] + kt*32);
        } else {
            #pragma unroll
            for (int p = 0; p < 4; ++p) xr[p] = *(const float4*)(xptr[p] + (kt-2)*32);
        }
        const float* w = wsrc + (size_t)kt*4096;
        #pragma unroll
        for (int p = 0; p < 4; ++p) wr[p] = *(const float4*)(w + p*1024);
        gr = *(const float4*)(gsrc + (size_t)kt*1024);
    };
    auto store_tile = [&]() {
        #pragma unroll
        for (int p = 0; p < 4; ++p) {
            int lin = p*256 + tid;
            int r = lin >> 3, c4 = lin & 7;
            int kb = c4*4;
            sXT[(kb+0)*132 + r] = xr[p].x;
            sXT[(kb+1)*132 + r] = xr[p].y;
            sXT[(kb+2)*132 + r] = xr[p].z;
            sXT[(kb+3)*132 + r] = xr[p].w;
            *(float4*)&sW[lin*4] = wr[p];
        }
        *(float4*)&sG[tid*4] = gr;
    };

    float acc[8][8];
    float accg[8][2];
    #pragma unroll
    for (int i = 0; i < 8; ++i) {
        #pragma unroll
        for (int j = 0; j < 8; ++j) acc[i][j] = 0.f;
        accg[i][0] = 0.f; accg[i][1] = 0.f;
    }

    // prologue: tile0 -> LDS, tile1 in flight
    load_tile(0);
    store_tile();
    load_tile(1);
    __syncthreads();

    #pragma unroll 1
    for (int kt = 0; kt < 10; ++kt) {
        #pragma unroll 8
        for (int k = 0; k < 32; ++k) {
            float4 A0 = *(const float4*)&sXT[k*132 + ty*8];
            float4 A1 = *(const float4*)&sXT[k*132 + ty*8 + 4];
            float4 b0 = *(const float4*)&sW[k*128 + tx*4];
            float4 b1 = *(const float4*)&sW[k*128 + 64 + tx*4];
            float2 gg = *(const float2*)&sG[k*32 + tx*2];
            float a[8] = {A0.x, A0.y, A0.z, A0.w, A1.x, A1.y, A1.z, A1.w};
            float b[8] = {b0.x, b0.y, b0.z, b0.w, b1.x, b1.y, b1.z, b1.w};
            #pragma unroll
            for (int rr = 0; rr < 8; ++rr) {
                #pragma unroll
                for (int cc = 0; cc < 8; ++cc)
                    acc[rr][cc] += a[rr] * b[cc];
                accg[rr][0] += a[rr] * gg.x;
                accg[rr][1] += a[rr] * gg.y;
            }
        }
        if (kt < 9) {
            __syncthreads();           // all reads of current tile done
            store_tile();              // tile kt+1 regs -> LDS (loads landed during compute)
            if (kt < 8) load_tile(kt + 2);   // issue next-next tile
            __syncthreads();           // tile kt+1 visible
        }
    }

    // ---- E0: per-thread scalar-branch leaky dot over own cols, reduce over tx ----
    {
        float4 wA = *(const float4*)&sWs2[32 + tx*4];
        float4 wB = *(const float4*)&sWs2[32 + 64 + tx*4];
        float wv[8] = {wA.x, wA.y, wA.z, wA.w, wB.x, wB.y, wB.z, wB.w};
        #pragma unroll
        for (int rr = 0; rr < 8; ++rr) {
            float p = 0.f;
            #pragma unroll
            for (int cc = 0; cc < 8; ++cc) {
                float s = acc[rr][cc];
                float l = (s >= 0.f) ? s : NSS*s;
                p += l * wv[cc];
            }
            p += __shfl_xor(p, 1);
            p += __shfl_xor(p, 2);
            p += __shfl_xor(p, 4);
            p += __shfl_xor(p, 8);
            if (tx == 0) sSca[ty*8 + rr] = p;
        }
    }

    // ---- E1/E2/E3 on two 64-row chunks ----
    const float bg0 = bg[tx*2], bg1 = bg[tx*2 + 1];
    const int lr2 = tid >> 2, q = tid & 3;

    #pragma unroll 1
    for (int ch = 0; ch < 2; ++ch) {
        __syncthreads();   // sV safe to overwrite (also orders sSca writes before E3 reads)

        // E1: gate -> v1, rows owned by ty-half
        if ((ty >> 3) == ch) {
            int tyl = ty & 7;
            #pragma unroll
            for (int rr = 0; rr < 8; ++rr) {
                int lr = tyl*8 + rr;
                int m = row0 + ch*64 + lr; if (m >= M) m = M - 1;
                const float* op = ovec_ws + (size_t)m*96 + tx*6;
                float g0 = 1.f / (1.f + __expf(-(accg[rr][0] + bg0)));
                float g1 = 1.f / (1.f + __expf(-(accg[rr][1] + bg1)));
                float* vd = &sV[lr*101 + tx*6];
                vd[0] = g0*op[0]; vd[1] = g0*op[1]; vd[2] = g0*op[2];
                vd[3] = g1*op[3]; vd[4] = g1*op[4]; vd[5] = g1*op[5];
            }
        }
        __syncthreads();

        // E2: d GEMM + VN leaky relu. thread = (lr2: row 0..63, q: 8 o's)
        float dd[8][3];
        #pragma unroll
        for (int a = 0; a < 8; ++a)
            #pragma unroll
            for (int x = 0; x < 3; ++x) dd[a][x] = 0.f;
        for (int c = 0; c < 32; ++c) {
            float vx = sV[lr2*101 + c*3 + 0];
            float vy = sV[lr2*101 + c*3 + 1];
            float vz = sV[lr2*101 + c*3 + 2];
            float4 w0 = *(const float4*)&sWd[c*32 + q*8];
            float4 w1 = *(const float4*)&sWd[c*32 + q*8 + 4];
            float wv[8] = {w0.x, w0.y, w0.z, w0.w, w1.x, w1.y, w1.z, w1.w};
            #pragma unroll
            for (int oo = 0; oo < 8; ++oo) {
                dd[oo][0] += vx*wv[oo];
                dd[oo][1] += vy*wv[oo];
                dd[oo][2] += vz*wv[oo];
            }
        }
        float v2[8][3];
        #pragma unroll
        for (int oo = 0; oo < 8; ++oo) {
            int o = q*8 + oo;
            float v1x = sV[lr2*101 + o*3 + 0];
            float v1y = sV[lr2*101 + o*3 + 1];
            float v1z = sV[lr2*101 + o*3 + 2];
            float dot = v1x*dd[oo][0] + v1y*dd[oo][1] + v1z*dd[oo][2];
            float dsq = dd[oo][0]*dd[oo][0] + dd[oo][1]*dd[oo][1] + dd[oo][2]*dd[oo][2];
            float coef = dot / (dsq + 1e-6f);
            float px = v1x - coef*dd[oo][0];
            float py = v1y - coef*dd[oo][1];
            float pz = v1z - coef*dd[oo][2];
            v2[oo][0] = NSV*v1x + (1.f - NSV)*((dot >= 0.f) ? v1x : px);
            v2[oo][1] = NSV*v1y + (1.f - NSV)*((dot >= 0.f) ? v1y : py);
            v2[oo][2] = NSV*v1z + (1.f - NSV)*((dot >= 0.f) ? v1z : pz);
        }
        __syncthreads();   // all E2 reads of sV done
        #pragma unroll
        for (int oo = 0; oo < 8; ++oo) {
            sV[lr2*101 + (q*8+oo)*3 + 0] = v2[oo][0];
            sV[lr2*101 + (q*8+oo)*3 + 1] = v2[oo][1];
            sV[lr2*101 + (q*8+oo)*3 + 2] = v2[oo][2];
        }
        __syncthreads();

        // E3: vh2 GEMM + vnorm dot + output
        float h2[8][3];
        #pragma unroll
        for (int a = 0; a < 8; ++a)
            #pragma unroll
            for (int x = 0; x < 3; ++x) h2[a][x] = 0.f;
        for (int c = 0; c < 32; ++c) {
            float vx = sV[lr2*101 + c*3 + 0];
            float vy = sV[lr2*101 + c*3 + 1];
            float vz = sV[lr2*101 + c*3 + 2];
            float4 w0 = *(const float4*)&sW12[c*32 + q*8];
            float4 w1 = *(const float4*)&sW12[c*32 + q*8 + 4];
            float wv[8] = {w0.x, w0.y, w0.z, w0.w, w1.x, w1.y, w1.z, w1.w};
            #pragma unroll
            for (int hh = 0; hh < 8; ++hh) {
                h2[hh][0] += vx*wv[hh];
                h2[hh][1] += vy*wv[hh];
                h2[hh][2] += vz*wv[hh];
            }
        }
        float partial = 0.f;
        #pragma unroll
        for (int hh = 0; hh < 8; ++hh) {
            float vn = sqrtf(h2[hh][0]*h2[hh][0] + h2[hh][1]*h2[hh][1] + h2[hh][2]*h2[hh][2]);
            partial += vn * sWs2[q*8 + hh];
        }
        partial += __shfl_xor(partial, 1);
        partial += __shfl_xor(partial, 2);
        int m = row0 + ch*64 + lr2;
        if (q == 0 && m < M) out[m] = partial + sSca[ch*64 + lr2];
    }
}

extern "C" void kernel_launch(void* const* d_in, const int* in_sizes, int n_in,
                              void* d_out, int out_size, void* d_ws, size_t ws_size,
                              hipStream_t stream) {
    const float* hsca  = (const float*)d_in[0];
    const float* hvec  = (const float*)d_in[1];
    const int*   idx   = (const int*)d_in[2];
    const float* Wv1_1 = (const float*)d_in[3];
    const float* Wv2_1 = (const float*)d_in[4];
    const float* Ws_1  = (const float*)d_in[5];
    const float* Wg_1  = (const float*)d_in[6];
    const float* bg_1  = (const float*)d_in[7];
    const float* Wd_1  = (const float*)d_in[8];
    const float* Wv1_2 = (const float*)d_in[9];
    // d_in[10] = Wv2_2 (unused: vec branch of layer 2 is dropped)
    const float* Ws_2  = (const float*)d_in[11];
    // d_in[12] = Wg_2, d_in[13] = bg_2 (unused)

    const int M = in_sizes[2];
    float* out = (float*)d_out;

    float* ws       = (float*)d_ws;
    float* vnorm_ws = ws;                      // M*64
    float* ovec_ws  = ws + (size_t)M*64;       // M*96
    float* wfuse_ws = ws + (size_t)M*160;      // 320*32

    const int nb32  = (M + 31) / 32;
    const int nb128 = (M + 127) / 128;

    k0_kernel<<<40, 256, 0, stream>>>(Ws_1, Wg_1, wfuse_ws);
    k1_kernel<<<nb32, 256, 0, stream>>>(hvec, idx, Wv1_1, Wv2_1, vnorm_ws, ovec_ws, M);
    k2_kernel<<<nb128, 256, 0, stream>>>(hsca, idx, Ws_1, vnorm_ws, ovec_ws, wfuse_ws,
                                         bg_1, Wd_1, Wv1_2, Ws_2, out, M);
}